// Round 1
// baseline (319.765 us; speedup 1.0000x reference)
//
#include <hip/hip_runtime.h>
#include <hip/hip_bf16.h>

typedef __attribute__((ext_vector_type(8))) short bf16x8;
typedef __attribute__((ext_vector_type(4))) short bf16x4;
typedef __attribute__((ext_vector_type(4))) float f32x4;

#define DEVI static __device__ __forceinline__

constexpr int NAG = 32, DIN = 256, HDIM = 128, ADIM = 32;
constexpr int G = 2;          // batch elems per block

// ws layout (bf16 element offsets)
constexpr int WS_ENC = 0;                  // 256x128 -> 32768
constexpr int WS_H   = 32768;              // 8 mats x 16384
constexpr int WS_QW  = 32768 + 8 * 16384;  // 163840, 4096 elems
constexpr int WS_TOT = WS_QW + 4096;       // 167936

DEVI short f2bf(float f) {
  union { float f; unsigned u; } a; a.f = f;
  unsigned r = (a.u + 0x7fffu + ((a.u >> 16) & 1u)) >> 16;
  return (short)r;
}

// ---------------- weight prep: fp32 row-major -> bf16 MFMA B-fragment order ----
// frag element e = ((ks*NT + nt)*64 + lane)*8 + j  maps to  W[ks*32+(lane>>4)*8+j][nt*16+(lane&15)]
__global__ void prep_weights(const float* __restrict__ enc_w,
                             const float* __restrict__ m0, const float* __restrict__ m1,
                             const float* __restrict__ m2, const float* __restrict__ m3,
                             const float* __restrict__ m4, const float* __restrict__ m5,
                             const float* __restrict__ m6, const float* __restrict__ m7,
                             const float* __restrict__ qw,
                             short* __restrict__ ws)
{
  const int i = blockIdx.x * 256 + threadIdx.x;
  if (i >= WS_TOT) return;
  const float* src; int Nout, e, base, sh, ntm;
  if (i < 32768) { src = enc_w; Nout = 128; e = i; base = 0; sh = 3; ntm = 7; }
  else if (i < WS_QW) {
    const int m = (i - 32768) >> 14;
    e = (i - 32768) & 16383; base = 32768 + (m << 14);
    const float* tab[8] = {m0, m1, m2, m3, m4, m5, m6, m7};
    src = tab[m]; Nout = 128; sh = 3; ntm = 7;
  } else { src = qw; Nout = 32; e = i - WS_QW; base = WS_QW; sh = 1; ntm = 1; }
  const int j = e & 7, lane = (e >> 3) & 63, tile = e >> 9;
  const int nt = tile & ntm, ks = tile >> sh;
  const int row = ks * 32 + (lane >> 4) * 8 + j;
  const int col = nt * 16 + (lane & 15);
  ws[base + e] = f2bf(src[row * Nout + col]);
}

// ---------------- generic fused linear: dst = act(src[64xK] @ W[KxH] + b) ------
// wave w computes output cols [32w, 32w+32)
template<int KSTEPS, bool RELU, bool TRANS>
DEVI void linearWG(const short* __restrict__ src, int sstride,
                   const short* __restrict__ wfrag, const float* __restrict__ bias,
                   short* __restrict__ dst, int dstride,
                   int wave, int lr, int lq)
{
  f32x4 acc[4][2];
#pragma unroll
  for (int mt = 0; mt < 4; ++mt)
#pragma unroll
    for (int t = 0; t < 2; ++t) acc[mt][t] = (f32x4){0.f, 0.f, 0.f, 0.f};

  const int lane = lq * 16 + lr;
  bf16x8 bf[KSTEPS][2];
  const bf16x8* wp = (const bf16x8*)wfrag;
#pragma unroll
  for (int ks = 0; ks < KSTEPS; ++ks)
#pragma unroll
    for (int t = 0; t < 2; ++t)
      bf[ks][t] = wp[(ks * 8 + wave * 2 + t) * 64 + lane];

#pragma unroll
  for (int ks = 0; ks < KSTEPS; ++ks) {
    bf16x8 af[4];
#pragma unroll
    for (int mt = 0; mt < 4; ++mt)
      af[mt] = *(const bf16x8*)(src + (mt * 16 + lr) * sstride + ks * 32 + lq * 8);
#pragma unroll
    for (int mt = 0; mt < 4; ++mt)
#pragma unroll
      for (int t = 0; t < 2; ++t)
        acc[mt][t] = __builtin_amdgcn_mfma_f32_16x16x32_bf16(af[mt], bf[ks][t], acc[mt][t], 0, 0, 0);
  }

#pragma unroll
  for (int t = 0; t < 2; ++t) {
    const int col = wave * 32 + t * 16 + lr;
    const float bv = bias[col];
#pragma unroll
    for (int mt = 0; mt < 4; ++mt) {
      if (!TRANS) {
#pragma unroll
        for (int r = 0; r < 4; ++r) {
          const int row = mt * 16 + lq * 4 + r;
          float v = acc[mt][t][r] + bv;
          if (RELU) v = fmaxf(v, 0.f);
          dst[row * dstride + col] = f2bf(v);
        }
      } else {           // transposed store (for v): dst[col][row], 4 consecutive rows
        bf16x4 s;
#pragma unroll
        for (int r = 0; r < 4; ++r) {
          float v = acc[mt][t][r] + bv;
          if (RELU) v = fmaxf(v, 0.f);
          s[r] = f2bf(v);
        }
        *(bf16x4*)(dst + col * dstride + mt * 16 + lq * 4) = s;
      }
    }
  }
}

// ---------------- one attention block, fully in LDS ----------------------------
DEVI void att_block(short* HB, short* AB, short* BB, short* AT, float* ST,
                    const short* wv, const short* wk, const short* wq, const short* wo,
                    const float* bv, const float* bk, const float* bq, const float* bo,
                    const float* __restrict__ mask, int b0,
                    int wave, int lr, int lq)
{
  linearWG<4, true, false>(HB, 136, wq, bq, AB, 136, wave, lr, lq);  // q -> AB
  linearWG<4, true, false>(HB, 136, wk, bk, BB, 136, wave, lr, lq);  // k -> BB
  __syncthreads();

  const int g = wave >> 1, half = wave & 1;
  float lg[2][4];
  {
    // scores[32x32] = q @ k^T for group g; this wave does cols [16*half,16*half+16)
    f32x4 sacc[2];
    sacc[0] = (f32x4){0, 0, 0, 0}; sacc[1] = (f32x4){0, 0, 0, 0};
#pragma unroll
    for (int ks = 0; ks < 4; ++ks) {
      const bf16x8 kf = *(const bf16x8*)(BB + (g * 32 + half * 16 + lr) * 136 + ks * 32 + lq * 8);
#pragma unroll
      for (int mt = 0; mt < 2; ++mt) {
        const bf16x8 qf = *(const bf16x8*)(AB + (g * 32 + mt * 16 + lr) * 136 + ks * 32 + lq * 8);
        sacc[mt] = __builtin_amdgcn_mfma_f32_16x16x32_bf16(qf, kf, sacc[mt], 0, 0, 0);
      }
    }
    // mask + in-register partial softmax (per-wave 16-col max & expsum)
    const float* mp = mask + (size_t)(b0 + g) * (NAG * NAG);
    float mx[2][4], sm[2][4];
#pragma unroll
    for (int mt = 0; mt < 2; ++mt)
#pragma unroll
      for (int r = 0; r < 4; ++r) {
        const int row = mt * 16 + lq * 4 + r, col = half * 16 + lr;
        const float m = mp[row * 32 + col];
        const float l = sacc[mt][r] * m - 9e15f * (1.f - m);
        lg[mt][r] = l;
        float v = l;
        v = fmaxf(v, __shfl_xor(v, 1)); v = fmaxf(v, __shfl_xor(v, 2));
        v = fmaxf(v, __shfl_xor(v, 4)); v = fmaxf(v, __shfl_xor(v, 8));
        mx[mt][r] = v;
        float e = __expf(l - v);
        e += __shfl_xor(e, 1); e += __shfl_xor(e, 2);
        e += __shfl_xor(e, 4); e += __shfl_xor(e, 8);
        sm[mt][r] = e;
      }
    if (lr == 0) {
#pragma unroll
      for (int mt = 0; mt < 2; ++mt)
#pragma unroll
        for (int r = 0; r < 4; ++r) {
          const int row = g * 32 + mt * 16 + lq * 4 + r;
          float2 p; p.x = mx[mt][r]; p.y = sm[mt][r];
          *(float2*)(ST + row * 4 + half * 2) = p;  // ST[row] = {m0,s0,m1,s1}
        }
    }
  }
  __syncthreads();
  {
    // combine halves, normalize, att -> AT (bf16, A-fragment friendly rows)
#pragma unroll
    for (int mt = 0; mt < 2; ++mt)
#pragma unroll
      for (int r = 0; r < 4; ++r) {
        const int row = g * 32 + mt * 16 + lq * 4 + r, col = half * 16 + lr;
        const float4 s4 = *(const float4*)(ST + row * 4);
        const float M = fmaxf(s4.x, s4.z);
        const float T = s4.y * __expf(s4.x - M) + s4.w * __expf(s4.z - M);
        const float a = __expf(lg[mt][r] - M) / T;
        AT[row * 40 + col] = f2bf(a);
      }
  }
  __syncthreads();

  // v -> BB stored TRANSPOSED as vT[128][72]
  linearWG<4, true, true>(HB, 136, wv, bv, BB, 72, wave, lr, lq);
  __syncthreads();

  {
    // out = att @ v  (per g: [32x32]x[32x128]); wave does cols [64*half, +64)
    f32x4 acc[2][4];
#pragma unroll
    for (int mt = 0; mt < 2; ++mt)
#pragma unroll
      for (int nt = 0; nt < 4; ++nt) acc[mt][nt] = (f32x4){0, 0, 0, 0};
    bf16x8 pa[2];
#pragma unroll
    for (int mt = 0; mt < 2; ++mt)
      pa[mt] = *(const bf16x8*)(AT + (g * 32 + mt * 16 + lr) * 40 + lq * 8);
#pragma unroll
    for (int nt = 0; nt < 4; ++nt) {
      const bf16x8 vf = *(const bf16x8*)(BB + (half * 64 + nt * 16 + lr) * 72 + g * 32 + lq * 8);
#pragma unroll
      for (int mt = 0; mt < 2; ++mt)
        acc[mt][nt] = __builtin_amdgcn_mfma_f32_16x16x32_bf16(pa[mt], vf, acc[mt][nt], 0, 0, 0);
    }
#pragma unroll
    for (int nt = 0; nt < 4; ++nt)
#pragma unroll
      for (int mt = 0; mt < 2; ++mt)
#pragma unroll
        for (int r = 0; r < 4; ++r) {
          const int row = g * 32 + mt * 16 + lq * 4 + r;
          const int col = half * 64 + nt * 16 + lr;
          AB[row * 136 + col] = f2bf(acc[mt][nt][r]);
        }
  }
  __syncthreads();

  linearWG<4, true, false>(AB, 136, wo, bo, HB, 136, wave, lr, lq);  // h' -> HB
  __syncthreads();
}

// ---------------- fused forward: one block = 2 batch elements ------------------
__global__ __launch_bounds__(256, 2)
void dgn_main(const float* __restrict__ x, const float* __restrict__ mask,
              const float* __restrict__ enc_b,
              const float* __restrict__ b1v, const float* __restrict__ b1k,
              const float* __restrict__ b1q, const float* __restrict__ b1o,
              const float* __restrict__ b2v, const float* __restrict__ b2k,
              const float* __restrict__ b2q, const float* __restrict__ b2o,
              const float* __restrict__ qb,
              const short* __restrict__ wf,
              float* __restrict__ out)
{
  __shared__ __align__(16) char smem[59392];
  short* HB = (short*)(smem);             // h   [64][136]
  short* AB = (short*)(smem + 17408);     // q / att-out [64][136]
  short* BB = (short*)(smem + 34816);     // k [64][136] / vT [128][72]
  short* AT = (short*)(smem + 53248);     // att bf16 [64][40]
  float* ST = (float*)(smem + 58368);     // softmax stats [64][2][2]
  short* XB = (short*)(smem + 17408);     // x staging [64][264] (aliases AB+BB)

  const int tid = threadIdx.x;
  const int wave = tid >> 6, lane = tid & 63;
  const int lr = lane & 15, lq = lane >> 4;
  const int b0 = blockIdx.x * G;

  // stage x (fp32 -> bf16) into XB
  {
    const float4* xsrc = (const float4*)(x + (size_t)b0 * NAG * DIN);
#pragma unroll
    for (int it = 0; it < 16; ++it) {
      const int q4 = tid + it * 256;
      const float4 v = xsrc[q4];
      const int row = q4 >> 6;
      const int col = (q4 & 63) * 4;
      bf16x4 s;
      s[0] = f2bf(v.x); s[1] = f2bf(v.y); s[2] = f2bf(v.z); s[3] = f2bf(v.w);
      *(bf16x4*)(XB + row * 264 + col) = s;
    }
  }
  __syncthreads();

  // encoder: h1 = relu(x @ enc_w + enc_b)
  linearWG<8, true, false>(XB, 264, wf + WS_ENC, enc_b, HB, 136, wave, lr, lq);
  __syncthreads();

  att_block(HB, AB, BB, AT, ST,
            wf + WS_H + 0 * 16384, wf + WS_H + 1 * 16384,
            wf + WS_H + 2 * 16384, wf + WS_H + 3 * 16384,
            b1v, b1k, b1q, b1o, mask, b0, wave, lr, lq);

  att_block(HB, AB, BB, AT, ST,
            wf + WS_H + 4 * 16384, wf + WS_H + 5 * 16384,
            wf + WS_H + 6 * 16384, wf + WS_H + 7 * 16384,
            b2v, b2k, b2q, b2o, mask, b0, wave, lr, lq);

  // head: out = h3 @ q_w + q_b   (no relu); wave w does rows [16w,16w+16)
  {
    f32x4 facc[2];
    facc[0] = (f32x4){0, 0, 0, 0}; facc[1] = (f32x4){0, 0, 0, 0};
    const bf16x8* wq = (const bf16x8*)(wf + WS_QW);
    bf16x8 bq[4][2];
#pragma unroll
    for (int ks = 0; ks < 4; ++ks)
#pragma unroll
      for (int t = 0; t < 2; ++t)
        bq[ks][t] = wq[(ks * 2 + t) * 64 + lane];
#pragma unroll
    for (int ks = 0; ks < 4; ++ks) {
      const bf16x8 af = *(const bf16x8*)(HB + (wave * 16 + lr) * 136 + ks * 32 + lq * 8);
      facc[0] = __builtin_amdgcn_mfma_f32_16x16x32_bf16(af, bq[ks][0], facc[0], 0, 0, 0);
      facc[1] = __builtin_amdgcn_mfma_f32_16x16x32_bf16(af, bq[ks][1], facc[1], 0, 0, 0);
    }
#pragma unroll
    for (int t = 0; t < 2; ++t) {
      const int col = t * 16 + lr;
      const float bvv = qb[col];
#pragma unroll
      for (int r = 0; r < 4; ++r) {
        const int row = wave * 16 + lq * 4 + r;            // 0..63
        const int g = row >> 5, ag = row & 31;
        out[(((size_t)(b0 + g) * NAG) + ag) * ADIM + col] = facc[t][r] + bvv;
      }
    }
  }
}

extern "C" void kernel_launch(void* const* d_in, const int* in_sizes, int n_in,
                              void* d_out, int out_size, void* d_ws, size_t ws_size,
                              hipStream_t stream)
{
  const float* x     = (const float*)d_in[0];
  const float* mask  = (const float*)d_in[1];
  const float* enc_w = (const float*)d_in[2];
  const float* enc_b = (const float*)d_in[3];
  const float* a1_vw = (const float*)d_in[4];
  const float* a1_vb = (const float*)d_in[5];
  const float* a1_kw = (const float*)d_in[6];
  const float* a1_kb = (const float*)d_in[7];
  const float* a1_qw = (const float*)d_in[8];
  const float* a1_qb = (const float*)d_in[9];
  const float* a1_ow = (const float*)d_in[10];
  const float* a1_ob = (const float*)d_in[11];
  const float* a2_vw = (const float*)d_in[12];
  const float* a2_vb = (const float*)d_in[13];
  const float* a2_kw = (const float*)d_in[14];
  const float* a2_kb = (const float*)d_in[15];
  const float* a2_qw = (const float*)d_in[16];
  const float* a2_qb = (const float*)d_in[17];
  const float* a2_ow = (const float*)d_in[18];
  const float* a2_ob = (const float*)d_in[19];
  const float* q_w   = (const float*)d_in[20];
  const float* q_b   = (const float*)d_in[21];
  short* ws = (short*)d_ws;

  prep_weights<<<(WS_TOT + 255) / 256, 256, 0, stream>>>(
      enc_w, a1_vw, a1_kw, a1_qw, a1_ow, a2_vw, a2_kw, a2_qw, a2_ow, q_w, ws);

  dgn_main<<<4096 / G, 256, 0, stream>>>(
      x, mask, enc_b,
      a1_vb, a1_kb, a1_qb, a1_ob,
      a2_vb, a2_kb, a2_qb, a2_ob,
      q_b, ws, (float*)d_out);
}